// Round 5
// baseline (149.798 us; speedup 1.0000x reference)
//
#include <hip/hip_runtime.h>
#include <hip/hip_bf16.h>
#include <stdint.h>

#define B_ 8
#define C_ 512
#define N_ 2048

typedef __bf16 bf16_t;
typedef bf16_t bf16x8 __attribute__((ext_vector_type(8)));
typedef bf16_t bf16x4 __attribute__((ext_vector_type(4)));
typedef float f32x4 __attribute__((ext_vector_type(4)));

// ---------------------------------------------------------------------------
// Cast two 512x512 weight matrices to bf16 (Wk, Wv -> contiguous).
// ---------------------------------------------------------------------------
__global__ __launch_bounds__(256) void cast_w_kernel(
    const float* __restrict__ w0, const float* __restrict__ w1,
    bf16_t* __restrict__ out)
{
    const float* src = (blockIdx.z == 0) ? w0 : w1;
    bf16_t* dst = out + (size_t)blockIdx.z * (C_ * C_);
    int i = (blockIdx.x * 256 + threadIdx.x) * 4;
    float4 f = *(const float4*)(src + i);
    bf16x4 o;
    o[0] = (bf16_t)f.x; o[1] = (bf16_t)f.y; o[2] = (bf16_t)f.z; o[3] = (bf16_t)f.w;
    *(bf16x4*)(dst + i) = o;
}

// ---------------------------------------------------------------------------
// Transpose-cast Wq: fp32 [C][C] -> bf16 out[i][c] = in[c][i]. grid (8,8).
// ---------------------------------------------------------------------------
__global__ __launch_bounds__(256) void transpose_cast_w_kernel(
    const float* __restrict__ in, bf16_t* __restrict__ out)
{
    __shared__ bf16_t tile[64][65];
    const int i0 = blockIdx.x * 64;
    const int c0 = blockIdx.y * 64;
    const int t = threadIdx.x;
    const int cx = (t & 15) * 4;
    const int ry = t >> 4;
#pragma unroll
    for (int r = ry; r < 64; r += 16) {
        float4 f = *(const float4*)&in[(size_t)(c0 + r) * C_ + i0 + cx];
        tile[r][cx + 0] = (bf16_t)f.x;
        tile[r][cx + 1] = (bf16_t)f.y;
        tile[r][cx + 2] = (bf16_t)f.z;
        tile[r][cx + 3] = (bf16_t)f.w;
    }
    __syncthreads();
    const int c4 = (t & 15) * 4;
    const int rb = t >> 4;
#pragma unroll
    for (int r = rb; r < 64; r += 16) {
        bf16x4 o;
        o[0] = tile[c4 + 0][r];
        o[1] = tile[c4 + 1][r];
        o[2] = tile[c4 + 2][r];
        o[3] = tile[c4 + 3][r];
        *(bf16x4*)&out[(size_t)(i0 + r) * C_ + c0 + c4] = o;
    }
}

// ---------------------------------------------------------------------------
// Fused-transpose projection GEMM, single-buffer LDS, 2 barriers per K-step
// (the proven race-free structure), with register prefetch of X(t+1) issued
// between barrier-1 and compute(t) (wave-private -> race-free pipelining).
//   P[c,n] = sum_i A[c,i] * X[b,i,n]
// A bf16 [512,512] via global_load_lds with SOURCE k-chunk pre-swizzle
// (LDS linear, reads XOR-swizzled -> conflict-free).  X fp32 cast+transposed
// into XOR-swizzled Bs.
// EPI 1: bf16 out + bias[row] (half-select K/V).  EPI 3: fp32 + bias[bz*C+row] + resid.
// blockIdx.z: half = z>>3 selects {A0,X0,C0,b0} vs {A1,X1,C1,b1}; bz = z&7.
// K = C_ = 512 fixed (8 K-steps of 64).
// ---------------------------------------------------------------------------
template <int EPI>
__global__ __launch_bounds__(256, 4) void proj_gemm(
    const bf16_t* __restrict__ A0, const bf16_t* __restrict__ A1,
    const float* __restrict__ X0, const float* __restrict__ X1,
    void* __restrict__ Cd0, void* __restrict__ Cd1,
    const float* __restrict__ bias0, const float* __restrict__ bias1,
    const float* __restrict__ resid, size_t sAb, int bstride)
{
    __shared__ __align__(16) bf16_t As[128 * 64];   // 16 KB
    __shared__ __align__(16) char  Bs[128 * 128];   // 16 KB

    const int tid  = threadIdx.x;
    const int lane = tid & 63;
    const int wave = tid >> 6;
    const int wr = wave >> 1, wc = wave & 1;
    const int half = blockIdx.z >> 3;
    const int bz = blockIdx.z & 7;
    const int m0 = blockIdx.y * 128;
    const int n0 = blockIdx.x * 128;

    const bf16_t* A = (half ? A1 : A0) + (size_t)bz * sAb;
    const float*  X = (half ? X1 : X0) + (size_t)bz * ((size_t)C_ * N_);
    const float*  bias = half ? bias1 : bias0;

    f32x4 acc[4][4];
#pragma unroll
    for (int i = 0; i < 4; ++i)
#pragma unroll
        for (int j = 0; j < 4; ++j) acc[i][j] = 0.f;

    // A staging: lane-linear LDS dest; source k-chunk pre-swizzled so LDS
    // slot (row r, chunk s) holds k-chunk s^(r&7)  [rule #21]
    const int srow  = tid >> 3;                         // 0..31
    const int scolA = ((tid & 7) ^ (srow & 7)) * 8;     // swizzled k offset
    const int ldsA  = tid * 16;                         // byte, +p*4096

    // X staging coords
    const int sa  = lane >> 3;                          // 0..7 -> i-pair 2*sa
    const int snl = wave * 32 + (lane & 7) * 4;         // n position (4 floats)

    float4 xf0[4], xf1[4];

    auto stage_a = [&](int t) {
        const bf16_t* ga = A + (size_t)(m0 + srow) * C_ + t * 64 + scolA;
#pragma unroll
        for (int p = 0; p < 4; ++p)
            __builtin_amdgcn_global_load_lds(
                (const __attribute__((address_space(1))) void*)(ga + (size_t)p * 32 * C_),
                (__attribute__((address_space(3))) void*)((char*)As + ldsA + p * 4096),
                16, 0, 0);
    };
    auto load_x = [&](int t) {
#pragma unroll
        for (int p = 0; p < 4; ++p) {
            const int iL = 16 * p + 2 * sa;
            const float* g0 = X + (size_t)(t * 64 + iL) * N_ + n0 + snl;
            xf0[p] = *(const float4*)g0;
            xf1[p] = *(const float4*)(g0 + N_);
        }
    };
    auto write_b = [&]() {
#pragma unroll
        for (int p = 0; p < 4; ++p) {
            const int iL = 16 * p + 2 * sa;
#pragma unroll
            for (int j = 0; j < 4; ++j) {
                const int n = snl + j;
                const int g = ((n ^ (n >> 3)) & 7) << 4;
                const int off = n * 128 + ((2 * iL) ^ g);
                union { bf16_t h[2]; uint32_t u; } pk;
                pk.h[0] = (bf16_t)((&xf0[p].x)[j]);
                pk.h[1] = (bf16_t)((&xf1[p].x)[j]);
                *(uint32_t*)(Bs + off) = pk.u;
            }
        }
    };
    auto compute = [&]() {
#pragma unroll
        for (int kk = 0; kk < 64; kk += 32) {
            bf16x8 af[4], bfr[4];
            const int kcol = kk + (lane >> 4) * 8;
            const int kc = kcol >> 3;
#pragma unroll
            for (int m = 0; m < 4; ++m) {
                const int row = wr * 64 + (lane & 15) + m * 16;
                af[m] = *(const bf16x8*)((const char*)As + row * 128 +
                                         ((kc ^ (row & 7)) << 4));
            }
#pragma unroll
            for (int n = 0; n < 4; ++n) {
                const int row = wc * 64 + (lane & 15) + n * 16;
                const int g = ((row ^ (row >> 3)) & 7) << 4;
                bfr[n] = *(const bf16x8*)(Bs + row * 128 + ((2 * kcol) ^ g));
            }
#pragma unroll
            for (int m = 0; m < 4; ++m)
#pragma unroll
                for (int n = 0; n < 4; ++n)
                    acc[m][n] = __builtin_amdgcn_mfma_f32_16x16x32_bf16(
                        af[m], bfr[n], acc[m][n], 0, 0, 0);
        }
    };

    // single-buffer, 2 barriers/K-step; X(t+1) prefetched into registers
    load_x(0);
#pragma unroll
    for (int t = 0; t < 8; ++t) {
        stage_a(t);          // DMA -> As (readers of tile t-1 done: barrier-2)
        write_b();           // regs(tile t) -> Bs
        __syncthreads();     // barrier-1: drains DMA (vmcnt) + ds_writes
        if (t < 7) load_x(t + 1);   // global->reg prefetch, hidden by compute
        compute();
        __syncthreads();     // barrier-2: all reads of tile t complete
    }

    const int rj = (lane >> 4) * 4;
    const int cc = lane & 15;
    void* Csel = half ? Cd1 : Cd0;
#pragma unroll
    for (int m = 0; m < 4; ++m) {
#pragma unroll
        for (int n = 0; n < 4; ++n) {
            const int col = n0 + wc * 64 + n * 16 + cc;
            f32x4 vv = acc[m][n];
#pragma unroll
            for (int j = 0; j < 4; ++j) {
                const int row = m0 + wr * 64 + m * 16 + rj + j;
                float val = vv[j] + bias[bstride * bz + row];
                const size_t o = (size_t)bz * ((size_t)C_ * N_) + (size_t)row * N_ + col;
                if (EPI == 3) {
                    ((float*)Csel)[o] = val + resid[o];
                } else {
                    ((bf16_t*)Csel)[o] = (bf16_t)val;
                }
            }
        }
    }
}

// ---------------------------------------------------------------------------
// NT bf16 GEMM with split-K: C[m,n] = sum_k A[m,k]*B[n,k], bf16 out.
// Single-buffer LDS, 2 barriers per K-step (proven structure), with
// source-pre-swizzled global_load_lds both sides + swizzled conflict-free reads.
// blockIdx.z = batch*SPLITS + split.
// ---------------------------------------------------------------------------
template <int SPLITS>
__global__ __launch_bounds__(256, 2) void gemm_nt(
    const bf16_t* __restrict__ A, const bf16_t* __restrict__ Bm,
    bf16_t* __restrict__ Cout,
    int Nn, int K, size_t sA, size_t sB, size_t sC)
{
    __shared__ __align__(16) bf16_t As[128 * 64];
    __shared__ __align__(16) bf16_t Bs2[128 * 64];

    const int tid  = threadIdx.x;
    const int lane = tid & 63;
    const int wave = tid >> 6;
    const int wr = wave >> 1, wc = wave & 1;
    const int bz = blockIdx.z / SPLITS;
    const int sp = blockIdx.z % SPLITS;
    const int kbeg = sp * (K / SPLITS);
    const int nt = (K / SPLITS) / 64;

    const bf16_t* Ab = A + (size_t)bz * sA;
    const bf16_t* Bb = Bm + (size_t)bz * sB;
    const int m0 = blockIdx.y * 128;
    const int n0 = blockIdx.x * 128;

    f32x4 acc[4][4];
#pragma unroll
    for (int i = 0; i < 4; ++i)
#pragma unroll
        for (int j = 0; j < 4; ++j) acc[i][j] = 0.f;

    const int srow = tid >> 3;
    const int scol = ((tid & 7) ^ (srow & 7)) * 8;
    const int ldso = tid * 16;

    for (int t = 0; t < nt; ++t) {
        const bf16_t* ga = Ab + (size_t)(m0 + srow) * K + kbeg + t * 64 + scol;
        const bf16_t* gb = Bb + (size_t)(n0 + srow) * K + kbeg + t * 64 + scol;
#pragma unroll
        for (int p = 0; p < 4; ++p)
            __builtin_amdgcn_global_load_lds(
                (const __attribute__((address_space(1))) void*)(ga + (size_t)p * 32 * K),
                (__attribute__((address_space(3))) void*)((char*)As + ldso + p * 4096),
                16, 0, 0);
#pragma unroll
        for (int p = 0; p < 4; ++p)
            __builtin_amdgcn_global_load_lds(
                (const __attribute__((address_space(1))) void*)(gb + (size_t)p * 32 * K),
                (__attribute__((address_space(3))) void*)((char*)Bs2 + ldso + p * 4096),
                16, 0, 0);
        __syncthreads();

#pragma unroll
        for (int kk = 0; kk < 64; kk += 32) {
            bf16x8 af[4], bfr[4];
            const int kcol = kk + (lane >> 4) * 8;
            const int kc = kcol >> 3;
#pragma unroll
            for (int m = 0; m < 4; ++m) {
                const int row = wr * 64 + (lane & 15) + m * 16;
                af[m] = *(const bf16x8*)((const char*)As + row * 128 +
                                         ((kc ^ (row & 7)) << 4));
            }
#pragma unroll
            for (int n = 0; n < 4; ++n) {
                const int row = wc * 64 + (lane & 15) + n * 16;
                bfr[n] = *(const bf16x8*)((const char*)Bs2 + row * 128 +
                                          ((kc ^ (row & 7)) << 4));
            }
#pragma unroll
            for (int m = 0; m < 4; ++m)
#pragma unroll
                for (int n = 0; n < 4; ++n)
                    acc[m][n] = __builtin_amdgcn_mfma_f32_16x16x32_bf16(
                        af[m], bfr[n], acc[m][n], 0, 0, 0);
        }
        __syncthreads();
    }

    const int rj = (lane >> 4) * 4;
    const int cc = lane & 15;
#pragma unroll
    for (int m = 0; m < 4; ++m) {
#pragma unroll
        for (int n = 0; n < 4; ++n) {
            const int col = n0 + wc * 64 + n * 16 + cc;
            f32x4 vv = acc[m][n];
#pragma unroll
            for (int j = 0; j < 4; ++j) {
                const int row = m0 + wr * 64 + m * 16 + rj + j;
                Cout[(size_t)blockIdx.z * sC + (size_t)row * Nn + col] = (bf16_t)vv[j];
            }
        }
    }
}

// ---------------------------------------------------------------------------
// Sum 4 split-K bf16 partials -> bf16. Pt: [B_][4][C_*C_], Out: [B_][C_*C_].
// ---------------------------------------------------------------------------
__global__ __launch_bounds__(256) void reduce_splitk_kernel(
    const bf16_t* __restrict__ Pt, bf16_t* __restrict__ Out)
{
    const size_t sCC = (size_t)C_ * C_;
    size_t idx = ((size_t)blockIdx.x * 256 + threadIdx.x) * 8;
    size_t b = idx / sCC;
    size_t r = idx - b * sCC;
    const bf16_t* base = Pt + (b * 4) * sCC + r;
    float acc[8];
#pragma unroll
    for (int j = 0; j < 8; ++j) acc[j] = 0.f;
#pragma unroll
    for (int s = 0; s < 4; ++s) {
        bf16x8 pv = *(const bf16x8*)(base + (size_t)s * sCC);
#pragma unroll
        for (int j = 0; j < 8; ++j) acc[j] += (float)pv[j];
    }
    bf16x8 o;
#pragma unroll
    for (int j = 0; j < 8; ++j) o[j] = (bf16_t)acc[j];
    *(bf16x8*)(Out + idx) = o;
}

// ---------------------------------------------------------------------------
// h[b][c] = sum_c1 St[b][c,c1] * bq[c1].
// ---------------------------------------------------------------------------
__global__ __launch_bounds__(256) void compute_h_kernel(
    const bf16_t* __restrict__ St, const float* __restrict__ bq,
    float* __restrict__ h)
{
    const int b = blockIdx.x;
    const int c = threadIdx.x * 2;
#pragma unroll
    for (int rr = 0; rr < 2; ++rr) {
        const bf16_t* row = St + ((size_t)b * C_ + c + rr) * C_;
        float acc = 0.f;
        for (int j = 0; j < C_; j += 8) {
            bf16x8 vv = *(const bf16x8*)(row + j);
#pragma unroll
            for (int t = 0; t < 8; ++t) acc += (float)vv[t] * bq[j + t];
        }
        h[b * C_ + c + rr] = acc;
    }
}

// ---------------------------------------------------------------------------
extern "C" void kernel_launch(void* const* d_in, const int* in_sizes, int n_in,
                              void* d_out, int out_size, void* d_ws, size_t ws_size,
                              hipStream_t stream)
{
    (void)in_sizes; (void)n_in; (void)out_size; (void)ws_size;
    const float* q  = (const float*)d_in[0];
    const float* k  = (const float*)d_in[1];
    const float* v  = (const float*)d_in[2];
    const float* wq = (const float*)d_in[3];
    const float* bq = (const float*)d_in[4];
    const float* wk = (const float*)d_in[5];
    const float* bk = (const float*)d_in[6];
    const float* wv = (const float*)d_in[7];
    const float* bv = (const float*)d_in[8];
    float* out = (float*)d_out;

    char* ws = (char*)d_ws;
    const size_t WSZ = (size_t)C_ * C_ * 2;            // 512 KB
    const size_t TSZ = (size_t)B_ * N_ * C_ * 2;       // 16.78 MB
    const size_t SCZ = (size_t)B_ * C_ * C_ * 2;       // 4.19 MB
    bf16_t* Wkb  = (bf16_t*)(ws);                      // Wk,Wv contiguous
    bf16_t* Wvb  = (bf16_t*)(ws + WSZ);
    bf16_t* WqTb = (bf16_t*)(ws + 2 * WSZ);
    bf16_t* Pk   = (bf16_t*)(ws + 3 * WSZ);
    bf16_t* Pv   = (bf16_t*)(ws + 3 * WSZ + TSZ);
    bf16_t* Stp  = (bf16_t*)(ws + 3 * WSZ + 2 * TSZ);  // split-K partials (St)
    bf16_t* Hp   = (bf16_t*)(ws + 3 * WSZ + 3 * TSZ);  // split-K partials (H)
    bf16_t* St   = (bf16_t*)(ws + 3 * WSZ + 4 * TSZ);
    bf16_t* HT   = (bf16_t*)(ws + 3 * WSZ + 4 * TSZ + SCZ);
    float*  hb   = (float*)(ws + 3 * WSZ + 4 * TSZ + 2 * SCZ);

    const dim3 blk(256);
    const size_t sBN = (size_t)N_ * C_;
    const size_t sCC = (size_t)C_ * C_;

    // 1. Wk, Wv -> bf16; WqT = Wq^T bf16
    cast_w_kernel<<<dim3(256, 1, 2), blk, 0, stream>>>(wk, wv, Wkb);
    transpose_cast_w_kernel<<<dim3(C_ / 64, C_ / 64), blk, 0, stream>>>(wq, WqTb);

    // 2. Fused K+V projections: Pk = Wk*k + bk, Pv = Wv*v + bv (bf16 [C,N])
    proj_gemm<1><<<dim3(N_ / 128, C_ / 128, 2 * B_), blk, 0, stream>>>(
        Wkb, Wvb, k, v, (void*)Pk, (void*)Pv, bk, bv, nullptr, 0, 0);

    // 3. St[c,c'] = sum_n Pv[c,n] * Pk[c',n]  (split-K 4 + reduce)
    gemm_nt<4><<<dim3(C_ / 128, C_ / 128, B_ * 4), blk, 0, stream>>>(
        Pv, Pk, Stp, C_, N_, sBN, sBN, sCC);
    reduce_splitk_kernel<<<dim3((B_ * sCC) / (256 * 8)), blk, 0, stream>>>(Stp, St);

    // 4. HT[c,i] = sum_c' St[c,c'] * WqT[i,c']  (split-K 4 + reduce); h = St.bq
    gemm_nt<4><<<dim3(C_ / 128, C_ / 128, B_ * 4), blk, 0, stream>>>(
        St, WqTb, Hp, C_, C_, sCC, 0, sCC);
    reduce_splitk_kernel<<<dim3((B_ * sCC) / (256 * 8)), blk, 0, stream>>>(Hp, HT);
    compute_h_kernel<<<dim3(B_), blk, 0, stream>>>(St, bq, hb);

    // 5. out[c,n] = sum_i HT[c,i] * q[i,n] + h[b][c] + q[c,n]  (fp32 final)
    proj_gemm<3><<<dim3(N_ / 128, C_ / 128, B_), blk, 0, stream>>>(
        HT, HT, q, q, (void*)out, (void*)out, hb, hb, q, sCC, C_);
}

// Round 6
// 127.671 us; speedup vs baseline: 1.1733x; 1.1733x over previous
//
#include <hip/hip_runtime.h>
#include <hip/hip_bf16.h>
#include <stdint.h>

#define B_ 8
#define C_ 512
#define N_ 2048

typedef __bf16 bf16_t;
typedef bf16_t bf16x8 __attribute__((ext_vector_type(8)));
typedef bf16_t bf16x4 __attribute__((ext_vector_type(4)));
typedef float f32x4 __attribute__((ext_vector_type(4)));

// ---------------------------------------------------------------------------
// Cast two 512x512 weight matrices to bf16 (Wk, Wv -> contiguous).
// ---------------------------------------------------------------------------
__global__ __launch_bounds__(256) void cast_w_kernel(
    const float* __restrict__ w0, const float* __restrict__ w1,
    bf16_t* __restrict__ out)
{
    const float* src = (blockIdx.z == 0) ? w0 : w1;
    bf16_t* dst = out + (size_t)blockIdx.z * (C_ * C_);
    int i = (blockIdx.x * 256 + threadIdx.x) * 4;
    float4 f = *(const float4*)(src + i);
    bf16x4 o;
    o[0] = (bf16_t)f.x; o[1] = (bf16_t)f.y; o[2] = (bf16_t)f.z; o[3] = (bf16_t)f.w;
    *(bf16x4*)(dst + i) = o;
}

// ---------------------------------------------------------------------------
// Transpose-cast Wq: fp32 [C][C] -> bf16 out[i][c] = in[c][i]. grid (8,8).
// ---------------------------------------------------------------------------
__global__ __launch_bounds__(256) void transpose_cast_w_kernel(
    const float* __restrict__ in, bf16_t* __restrict__ out)
{
    __shared__ bf16_t tile[64][65];
    const int i0 = blockIdx.x * 64;
    const int c0 = blockIdx.y * 64;
    const int t = threadIdx.x;
    const int cx = (t & 15) * 4;
    const int ry = t >> 4;
#pragma unroll
    for (int r = ry; r < 64; r += 16) {
        float4 f = *(const float4*)&in[(size_t)(c0 + r) * C_ + i0 + cx];
        tile[r][cx + 0] = (bf16_t)f.x;
        tile[r][cx + 1] = (bf16_t)f.y;
        tile[r][cx + 2] = (bf16_t)f.z;
        tile[r][cx + 3] = (bf16_t)f.w;
    }
    __syncthreads();
    const int c4 = (t & 15) * 4;
    const int rb = t >> 4;
#pragma unroll
    for (int r = rb; r < 64; r += 16) {
        bf16x4 o;
        o[0] = tile[c4 + 0][r];
        o[1] = tile[c4 + 1][r];
        o[2] = tile[c4 + 2][r];
        o[3] = tile[c4 + 3][r];
        *(bf16x4*)&out[(size_t)(i0 + r) * C_ + c0 + c4] = o;
    }
}

// ---------------------------------------------------------------------------
// Fused-transpose projection GEMM, single-buffer LDS, 2 barriers per K-step
// (proven race-free structure), register prefetch of X(t+1) issued between
// barrier-1 and compute(t) (wave-private -> race-free pipelining).
//   P[c,n] = sum_i A[c,i] * X[b,i,n]
// A bf16 [512,512] via global_load_lds with SOURCE k-chunk pre-swizzle
// (LDS linear, reads XOR-swizzled -> conflict-free).  X fp32 cast+transposed
// into XOR-swizzled Bs.
// EPI 1: bf16 out + bias[row] (half-select K/V).  EPI 3: fp32 + bias[bz*C+row] + resid.
// blockIdx.z: half = z>>3 selects {A0,X0,C0,b0} vs {A1,X1,C1,b1}; bz = z&7.
// K = C_ = 512 fixed (8 K-steps of 64).
// NOTE launch_bounds (256,2): VGPR cap 256. (256,4) forced 64 VGPR ->
// acc[4][4] (64 regs) + 32-reg prefetch spilled to scratch; dispatches went
// 45 -> 71 us (r5 post-mortem). Keep >= ~160 VGPR headroom here.
// ---------------------------------------------------------------------------
template <int EPI>
__global__ __launch_bounds__(256, 2) void proj_gemm(
    const bf16_t* __restrict__ A0, const bf16_t* __restrict__ A1,
    const float* __restrict__ X0, const float* __restrict__ X1,
    void* __restrict__ Cd0, void* __restrict__ Cd1,
    const float* __restrict__ bias0, const float* __restrict__ bias1,
    const float* __restrict__ resid, size_t sAb, int bstride)
{
    __shared__ __align__(16) bf16_t As[128 * 64];   // 16 KB
    __shared__ __align__(16) char  Bs[128 * 128];   // 16 KB

    const int tid  = threadIdx.x;
    const int lane = tid & 63;
    const int wave = tid >> 6;
    const int wr = wave >> 1, wc = wave & 1;
    const int half = blockIdx.z >> 3;
    const int bz = blockIdx.z & 7;
    const int m0 = blockIdx.y * 128;
    const int n0 = blockIdx.x * 128;

    const bf16_t* A = (half ? A1 : A0) + (size_t)bz * sAb;
    const float*  X = (half ? X1 : X0) + (size_t)bz * ((size_t)C_ * N_);
    const float*  bias = half ? bias1 : bias0;

    f32x4 acc[4][4];
#pragma unroll
    for (int i = 0; i < 4; ++i)
#pragma unroll
        for (int j = 0; j < 4; ++j) acc[i][j] = 0.f;

    // A staging: lane-linear LDS dest; source k-chunk pre-swizzled so LDS
    // slot (row r, chunk s) holds k-chunk s^(r&7)  [rule #21]
    const int srow  = tid >> 3;                         // 0..31
    const int scolA = ((tid & 7) ^ (srow & 7)) * 8;     // swizzled k offset
    const int ldsA  = tid * 16;                         // byte, +p*4096

    // X staging coords
    const int sa  = lane >> 3;                          // 0..7 -> i-pair 2*sa
    const int snl = wave * 32 + (lane & 7) * 4;         // n position (4 floats)

    float4 xf0[4], xf1[4];

    auto stage_a = [&](int t) {
        const bf16_t* ga = A + (size_t)(m0 + srow) * C_ + t * 64 + scolA;
#pragma unroll
        for (int p = 0; p < 4; ++p)
            __builtin_amdgcn_global_load_lds(
                (const __attribute__((address_space(1))) void*)(ga + (size_t)p * 32 * C_),
                (__attribute__((address_space(3))) void*)((char*)As + ldsA + p * 4096),
                16, 0, 0);
    };
    auto load_x = [&](int t) {
#pragma unroll
        for (int p = 0; p < 4; ++p) {
            const int iL = 16 * p + 2 * sa;
            const float* g0 = X + (size_t)(t * 64 + iL) * N_ + n0 + snl;
            xf0[p] = *(const float4*)g0;
            xf1[p] = *(const float4*)(g0 + N_);
        }
    };
    auto write_b = [&]() {
#pragma unroll
        for (int p = 0; p < 4; ++p) {
            const int iL = 16 * p + 2 * sa;
#pragma unroll
            for (int j = 0; j < 4; ++j) {
                const int n = snl + j;
                const int g = ((n ^ (n >> 3)) & 7) << 4;
                const int off = n * 128 + ((2 * iL) ^ g);
                union { bf16_t h[2]; uint32_t u; } pk;
                pk.h[0] = (bf16_t)((&xf0[p].x)[j]);
                pk.h[1] = (bf16_t)((&xf1[p].x)[j]);
                *(uint32_t*)(Bs + off) = pk.u;
            }
        }
    };
    auto compute = [&]() {
#pragma unroll
        for (int kk = 0; kk < 64; kk += 32) {
            bf16x8 af[4], bfr[4];
            const int kcol = kk + (lane >> 4) * 8;
            const int kc = kcol >> 3;
#pragma unroll
            for (int m = 0; m < 4; ++m) {
                const int row = wr * 64 + (lane & 15) + m * 16;
                af[m] = *(const bf16x8*)((const char*)As + row * 128 +
                                         ((kc ^ (row & 7)) << 4));
            }
#pragma unroll
            for (int n = 0; n < 4; ++n) {
                const int row = wc * 64 + (lane & 15) + n * 16;
                const int g = ((row ^ (row >> 3)) & 7) << 4;
                bfr[n] = *(const bf16x8*)(Bs + row * 128 + ((2 * kcol) ^ g));
            }
#pragma unroll
            for (int m = 0; m < 4; ++m)
#pragma unroll
                for (int n = 0; n < 4; ++n)
                    acc[m][n] = __builtin_amdgcn_mfma_f32_16x16x32_bf16(
                        af[m], bfr[n], acc[m][n], 0, 0, 0);
        }
    };

    // single-buffer, 2 barriers/K-step; X(t+1) prefetched into registers
    load_x(0);
#pragma unroll
    for (int t = 0; t < 8; ++t) {
        stage_a(t);          // DMA -> As (readers of tile t-1 done: barrier-2)
        write_b();           // regs(tile t) -> Bs
        __syncthreads();     // barrier-1: drains DMA (vmcnt) + ds_writes
        if (t < 7) load_x(t + 1);   // global->reg prefetch, hidden by compute
        compute();
        __syncthreads();     // barrier-2: all reads of tile t complete
    }

    const int rj = (lane >> 4) * 4;
    const int cc = lane & 15;
    void* Csel = half ? Cd1 : Cd0;
#pragma unroll
    for (int m = 0; m < 4; ++m) {
#pragma unroll
        for (int n = 0; n < 4; ++n) {
            const int col = n0 + wc * 64 + n * 16 + cc;
            f32x4 vv = acc[m][n];
#pragma unroll
            for (int j = 0; j < 4; ++j) {
                const int row = m0 + wr * 64 + m * 16 + rj + j;
                float val = vv[j] + bias[bstride * bz + row];
                const size_t o = (size_t)bz * ((size_t)C_ * N_) + (size_t)row * N_ + col;
                if (EPI == 3) {
                    ((float*)Csel)[o] = val + resid[o];
                } else {
                    ((bf16_t*)Csel)[o] = (bf16_t)val;
                }
            }
        }
    }
}

// ---------------------------------------------------------------------------
// NT bf16 GEMM with split-K: C[m,n] = sum_k A[m,k]*B[n,k], bf16 out.
// Single-buffer LDS, 2 barriers per K-step (proven structure), with
// source-pre-swizzled global_load_lds both sides + swizzled conflict-free reads.
// blockIdx.z = batch*SPLITS + split.
// ---------------------------------------------------------------------------
template <int SPLITS>
__global__ __launch_bounds__(256, 2) void gemm_nt(
    const bf16_t* __restrict__ A, const bf16_t* __restrict__ Bm,
    bf16_t* __restrict__ Cout,
    int Nn, int K, size_t sA, size_t sB, size_t sC)
{
    __shared__ __align__(16) bf16_t As[128 * 64];
    __shared__ __align__(16) bf16_t Bs2[128 * 64];

    const int tid  = threadIdx.x;
    const int lane = tid & 63;
    const int wave = tid >> 6;
    const int wr = wave >> 1, wc = wave & 1;
    const int bz = blockIdx.z / SPLITS;
    const int sp = blockIdx.z % SPLITS;
    const int kbeg = sp * (K / SPLITS);
    const int nt = (K / SPLITS) / 64;

    const bf16_t* Ab = A + (size_t)bz * sA;
    const bf16_t* Bb = Bm + (size_t)bz * sB;
    const int m0 = blockIdx.y * 128;
    const int n0 = blockIdx.x * 128;

    f32x4 acc[4][4];
#pragma unroll
    for (int i = 0; i < 4; ++i)
#pragma unroll
        for (int j = 0; j < 4; ++j) acc[i][j] = 0.f;

    const int srow = tid >> 3;
    const int scol = ((tid & 7) ^ (srow & 7)) * 8;
    const int ldso = tid * 16;

    for (int t = 0; t < nt; ++t) {
        const bf16_t* ga = Ab + (size_t)(m0 + srow) * K + kbeg + t * 64 + scol;
        const bf16_t* gb = Bb + (size_t)(n0 + srow) * K + kbeg + t * 64 + scol;
#pragma unroll
        for (int p = 0; p < 4; ++p)
            __builtin_amdgcn_global_load_lds(
                (const __attribute__((address_space(1))) void*)(ga + (size_t)p * 32 * K),
                (__attribute__((address_space(3))) void*)((char*)As + ldso + p * 4096),
                16, 0, 0);
#pragma unroll
        for (int p = 0; p < 4; ++p)
            __builtin_amdgcn_global_load_lds(
                (const __attribute__((address_space(1))) void*)(gb + (size_t)p * 32 * K),
                (__attribute__((address_space(3))) void*)((char*)Bs2 + ldso + p * 4096),
                16, 0, 0);
        __syncthreads();

#pragma unroll
        for (int kk = 0; kk < 64; kk += 32) {
            bf16x8 af[4], bfr[4];
            const int kcol = kk + (lane >> 4) * 8;
            const int kc = kcol >> 3;
#pragma unroll
            for (int m = 0; m < 4; ++m) {
                const int row = wr * 64 + (lane & 15) + m * 16;
                af[m] = *(const bf16x8*)((const char*)As + row * 128 +
                                         ((kc ^ (row & 7)) << 4));
            }
#pragma unroll
            for (int n = 0; n < 4; ++n) {
                const int row = wc * 64 + (lane & 15) + n * 16;
                bfr[n] = *(const bf16x8*)((const char*)Bs2 + row * 128 +
                                          ((kc ^ (row & 7)) << 4));
            }
#pragma unroll
            for (int m = 0; m < 4; ++m)
#pragma unroll
                for (int n = 0; n < 4; ++n)
                    acc[m][n] = __builtin_amdgcn_mfma_f32_16x16x32_bf16(
                        af[m], bfr[n], acc[m][n], 0, 0, 0);
        }
        __syncthreads();
    }

    const int rj = (lane >> 4) * 4;
    const int cc = lane & 15;
#pragma unroll
    for (int m = 0; m < 4; ++m) {
#pragma unroll
        for (int n = 0; n < 4; ++n) {
            const int col = n0 + wc * 64 + n * 16 + cc;
            f32x4 vv = acc[m][n];
#pragma unroll
            for (int j = 0; j < 4; ++j) {
                const int row = m0 + wr * 64 + m * 16 + rj + j;
                Cout[(size_t)blockIdx.z * sC + (size_t)row * Nn + col] = (bf16_t)vv[j];
            }
        }
    }
}

// ---------------------------------------------------------------------------
// Sum 4 split-K bf16 partials -> bf16. Pt: [B_][4][C_*C_], Out: [B_][C_*C_].
// ---------------------------------------------------------------------------
__global__ __launch_bounds__(256) void reduce_splitk_kernel(
    const bf16_t* __restrict__ Pt, bf16_t* __restrict__ Out)
{
    const size_t sCC = (size_t)C_ * C_;
    size_t idx = ((size_t)blockIdx.x * 256 + threadIdx.x) * 8;
    size_t b = idx / sCC;
    size_t r = idx - b * sCC;
    const bf16_t* base = Pt + (b * 4) * sCC + r;
    float acc[8];
#pragma unroll
    for (int j = 0; j < 8; ++j) acc[j] = 0.f;
#pragma unroll
    for (int s = 0; s < 4; ++s) {
        bf16x8 pv = *(const bf16x8*)(base + (size_t)s * sCC);
#pragma unroll
        for (int j = 0; j < 8; ++j) acc[j] += (float)pv[j];
    }
    bf16x8 o;
#pragma unroll
    for (int j = 0; j < 8; ++j) o[j] = (bf16_t)acc[j];
    *(bf16x8*)(Out + idx) = o;
}

// ---------------------------------------------------------------------------
// h[b][c] = sum_c1 St[b][c,c1] * bq[c1].
// ---------------------------------------------------------------------------
__global__ __launch_bounds__(256) void compute_h_kernel(
    const bf16_t* __restrict__ St, const float* __restrict__ bq,
    float* __restrict__ h)
{
    const int b = blockIdx.x;
    const int c = threadIdx.x * 2;
#pragma unroll
    for (int rr = 0; rr < 2; ++rr) {
        const bf16_t* row = St + ((size_t)b * C_ + c + rr) * C_;
        float acc = 0.f;
        for (int j = 0; j < C_; j += 8) {
            bf16x8 vv = *(const bf16x8*)(row + j);
#pragma unroll
            for (int t = 0; t < 8; ++t) acc += (float)vv[t] * bq[j + t];
        }
        h[b * C_ + c + rr] = acc;
    }
}

// ---------------------------------------------------------------------------
extern "C" void kernel_launch(void* const* d_in, const int* in_sizes, int n_in,
                              void* d_out, int out_size, void* d_ws, size_t ws_size,
                              hipStream_t stream)
{
    (void)in_sizes; (void)n_in; (void)out_size; (void)ws_size;
    const float* q  = (const float*)d_in[0];
    const float* k  = (const float*)d_in[1];
    const float* v  = (const float*)d_in[2];
    const float* wq = (const float*)d_in[3];
    const float* bq = (const float*)d_in[4];
    const float* wk = (const float*)d_in[5];
    const float* bk = (const float*)d_in[6];
    const float* wv = (const float*)d_in[7];
    const float* bv = (const float*)d_in[8];
    float* out = (float*)d_out;

    char* ws = (char*)d_ws;
    const size_t WSZ = (size_t)C_ * C_ * 2;            // 512 KB
    const size_t TSZ = (size_t)B_ * N_ * C_ * 2;       // 16.78 MB
    const size_t SCZ = (size_t)B_ * C_ * C_ * 2;       // 4.19 MB
    bf16_t* Wkb  = (bf16_t*)(ws);                      // Wk,Wv contiguous
    bf16_t* Wvb  = (bf16_t*)(ws + WSZ);
    bf16_t* WqTb = (bf16_t*)(ws + 2 * WSZ);
    bf16_t* Pk   = (bf16_t*)(ws + 3 * WSZ);
    bf16_t* Pv   = (bf16_t*)(ws + 3 * WSZ + TSZ);
    bf16_t* Stp  = (bf16_t*)(ws + 3 * WSZ + 2 * TSZ);  // split-K partials (St)
    bf16_t* Hp   = (bf16_t*)(ws + 3 * WSZ + 3 * TSZ);  // split-K partials (H)
    bf16_t* St   = (bf16_t*)(ws + 3 * WSZ + 4 * TSZ);
    bf16_t* HT   = (bf16_t*)(ws + 3 * WSZ + 4 * TSZ + SCZ);
    float*  hb   = (float*)(ws + 3 * WSZ + 4 * TSZ + 2 * SCZ);

    const dim3 blk(256);
    const size_t sBN = (size_t)N_ * C_;
    const size_t sCC = (size_t)C_ * C_;

    // 1. Wk, Wv -> bf16; WqT = Wq^T bf16
    cast_w_kernel<<<dim3(256, 1, 2), blk, 0, stream>>>(wk, wv, Wkb);
    transpose_cast_w_kernel<<<dim3(C_ / 64, C_ / 64), blk, 0, stream>>>(wq, WqTb);

    // 2. Fused K+V projections: Pk = Wk*k + bk, Pv = Wv*v + bv (bf16 [C,N])
    proj_gemm<1><<<dim3(N_ / 128, C_ / 128, 2 * B_), blk, 0, stream>>>(
        Wkb, Wvb, k, v, (void*)Pk, (void*)Pv, bk, bv, nullptr, 0, 0);

    // 3. St[c,c'] = sum_n Pv[c,n] * Pk[c',n]  (split-K 4 + reduce)
    gemm_nt<4><<<dim3(C_ / 128, C_ / 128, B_ * 4), blk, 0, stream>>>(
        Pv, Pk, Stp, C_, N_, sBN, sBN, sCC);
    reduce_splitk_kernel<<<dim3((B_ * sCC) / (256 * 8)), blk, 0, stream>>>(Stp, St);

    // 4. HT[c,i] = sum_c' St[c,c'] * WqT[i,c']  (split-K 4 + reduce); h = St.bq
    gemm_nt<4><<<dim3(C_ / 128, C_ / 128, B_ * 4), blk, 0, stream>>>(
        St, WqTb, Hp, C_, C_, sCC, 0, sCC);
    reduce_splitk_kernel<<<dim3((B_ * sCC) / (256 * 8)), blk, 0, stream>>>(Hp, HT);
    compute_h_kernel<<<dim3(B_), blk, 0, stream>>>(St, bq, hb);

    // 5. out[c,n] = sum_i HT[c,i] * q[i,n] + h[b][c] + q[c,n]  (fp32 final)
    proj_gemm<3><<<dim3(N_ / 128, C_ / 128, B_), blk, 0, stream>>>(
        HT, HT, q, q, (void*)out, (void*)out, hb, hb, q, sCC, C_);
}